// Round 1
// baseline (598.226 us; speedup 1.0000x reference)
//
#include <hip/hip_runtime.h>
#include <hip/hip_cooperative_groups.h>
#include <math.h>

namespace cg = cooperative_groups;

#define G 2
#define BB 2
#define L 1024
#define DM 256
#define DI 512
#define DS 16
#define DR 16
#define CH 64              // chunks per sequence
#define CL 16              // L / CH
#define RTOT (G*BB*L)      // 4096 rows per layer-step
#define SKX 8              // x_proj split-K factor
#define YSTR 520           // Ys LDS row stride (shorts)
#define NBLK 256           // mega-kernel grid
#define NTHR 512           // mega-kernel block

#define NWIN  (4 * 2 * DI * DM)   // in_proj elements (4 layers)
#define NWOUT (4 * DM * DI)       // out_proj elements

typedef short bh8 __attribute__((ext_vector_type(8)));
typedef float f4x __attribute__((ext_vector_type(4)));

__device__ __forceinline__ float silu_f(float x) { return x / (1.f + __expf(-x)); }
__device__ __forceinline__ float softplus_f(float x) {
    return (x > 20.f) ? x : __logf(1.f + __expf(x));
}

__device__ __forceinline__ unsigned short f2bf(float f) {
    unsigned u = __float_as_uint(f);
    unsigned r = u + 0x7FFFu + ((u >> 16) & 1u);
    return (unsigned short)(r >> 16);
}
__device__ __forceinline__ float bf2f(unsigned short s) {
    return __uint_as_float(((unsigned)s) << 16);
}

// ---------------------------------------------------------------------------
// Shared-memory union for the mega-kernel phases. The SC struct persists from
// scanA through combine into scanB (same block = same chunk), carrying
// dbl / xc / dt so scanB needs no DBLc/XCb re-reads and no dt recompute.
// Total 101888 B -> 1 block/CU (fine: cooperative grid = 256 blocks).
// ---------------------------------------------------------------------------
struct SmemIP {                     // in_proj phase: two half-block tile sets
    short As_hi[2][128 * 40];
    short As_lo[2][128 * 40];
    short Bs_hi[2][64 * 40];
    short Bs_lo[2][64 * 40];
};
struct SmemXP {                     // x_proj phase
    float As[2][16][68];
    float Bs[2][16][68];
};
struct SmemSC {                     // scan phases (persists A -> B)
    float dbl[CL][48];
    float xcs[CL][DI];
    float dts[CL][DI];
    short Ys_hi[CL * YSTR];
    short Ys_lo[CL * YSTR];
};
union Smem {
    SmemIP ip;
    SmemXP xp;
    SmemSC sc;
};

// ---------------------------------------------------------------------------
// Phase: in_proj MFMA GEMM (3xbf16). 512 virtual 128x64 tiles mapped as two
// 256-thread half-blocks per mega-block. AMAP 1: A = x with g-dependent time
// reversal (step 0). AMAP 0: A = Pout as pre-split bf16 hi/lo (step 1).
// ---------------------------------------------------------------------------
template<int AMAP>
__device__ __forceinline__ void ip_phase(
    const float* __restrict__ Ax,
    const short* __restrict__ Ah, const short* __restrict__ Al,
    const short* __restrict__ Wh, const short* __restrict__ Wl,
    int step, float* __restrict__ C, Smem& sm, int blk, int tid)
{
    constexpr int Ktot = DM, Nout = 2 * DI, ldc = 1024;
    const int half = tid >> 8;
    const int t    = tid & 255;
    const int vb   = blk * 2 + half;        // 0..511
    const int row0 = (vb >> 4) * 128;
    const int col0 = (vb & 15) * 64;
    const int g    = row0 >> 11;
    const int lay  = g * 2 + step;
    const short* Whg = Wh + (size_t)lay * Nout * Ktot;
    const short* Wlg = Wl + (size_t)lay * Nout * Ktot;
    short* As_hi = sm.ip.As_hi[half];
    short* As_lo = sm.ip.As_lo[half];
    short* Bs_hi = sm.ip.Bs_hi[half];
    short* Bs_lo = sm.ip.Bs_lo[half];
    const int lane = t & 63, wv = t >> 6;
    const int m = lane & 15, quad = lane >> 4;
    const int wr = wv >> 1, wc = wv & 1;
    const int NT = Ktot / 32;     // 8

    float4 pa[4];
    short4 pah[4], pal[4], pbh[2], pbl[2];
    auto loadT = [&](int kt) {
        const int kb = kt * 32;
        #pragma unroll
        for (int i = 0; i < 4; i++) {
            int id = t + 256 * i;
            int row = id >> 3, kq = id & 7;
            if (AMAP == 1) {
                int gr = row0 + row;
                int gg = gr >> 11, b = (gr >> 10) & 1, l = gr & 1023;
                int sl = gg ? (1023 - l) : l;
                pa[i] = *(const float4*)&Ax[(size_t)(b * 1024 + sl) * Ktot + kb + kq * 4];
            } else {
                size_t o = (size_t)(row0 + row) * Ktot + kb + kq * 4;
                pah[i] = *(const short4*)&Ah[o];
                pal[i] = *(const short4*)&Al[o];
            }
        }
        #pragma unroll
        for (int i = 0; i < 2; i++) {
            int id = t + 256 * i;
            int row = id >> 3, kq = id & 7;
            size_t o = (size_t)(col0 + row) * Ktot + kb + kq * 4;
            pbh[i] = *(const short4*)&Whg[o];
            pbl[i] = *(const short4*)&Wlg[o];
        }
    };

    f4x acc[4][2] = {};
    loadT(0);

    for (int kt = 0; kt < NT; kt++) {
        #pragma unroll
        for (int i = 0; i < 4; i++) {
            int id = t + 256 * i;
            int row = id >> 3, kq = id & 7;
            if (AMAP == 1) {
                float4 v = pa[i];
                short4 h, l;
                unsigned short s;
                s = f2bf(v.x); h.x = (short)s; l.x = (short)f2bf(v.x - bf2f(s));
                s = f2bf(v.y); h.y = (short)s; l.y = (short)f2bf(v.y - bf2f(s));
                s = f2bf(v.z); h.z = (short)s; l.z = (short)f2bf(v.z - bf2f(s));
                s = f2bf(v.w); h.w = (short)s; l.w = (short)f2bf(v.w - bf2f(s));
                *(short4*)&As_hi[row * 40 + kq * 4] = h;
                *(short4*)&As_lo[row * 40 + kq * 4] = l;
            } else {
                *(short4*)&As_hi[row * 40 + kq * 4] = pah[i];
                *(short4*)&As_lo[row * 40 + kq * 4] = pal[i];
            }
        }
        #pragma unroll
        for (int i = 0; i < 2; i++) {
            int id = t + 256 * i;
            int row = id >> 3, kq = id & 7;
            *(short4*)&Bs_hi[row * 40 + kq * 4] = pbh[i];
            *(short4*)&Bs_lo[row * 40 + kq * 4] = pbl[i];
        }
        __syncthreads();
        if (kt + 1 < NT) loadT(kt + 1);

        bh8 ah[4], al[4], bh[2], bl[2];
        #pragma unroll
        for (int p = 0; p < 4; p++) {
            int r = wr * 64 + p * 16 + m;
            ah[p] = *(bh8*)&As_hi[r * 40 + quad * 8];
            al[p] = *(bh8*)&As_lo[r * 40 + quad * 8];
        }
        #pragma unroll
        for (int q = 0; q < 2; q++) {
            int r = wc * 32 + q * 16 + m;
            bh[q] = *(bh8*)&Bs_hi[r * 40 + quad * 8];
            bl[q] = *(bh8*)&Bs_lo[r * 40 + quad * 8];
        }
        #pragma unroll
        for (int p = 0; p < 4; p++)
            #pragma unroll
            for (int q = 0; q < 2; q++) {
                acc[p][q] = __builtin_amdgcn_mfma_f32_16x16x32_bf16(ah[p], bh[q], acc[p][q], 0, 0, 0);
                acc[p][q] = __builtin_amdgcn_mfma_f32_16x16x32_bf16(ah[p], bl[q], acc[p][q], 0, 0, 0);
                acc[p][q] = __builtin_amdgcn_mfma_f32_16x16x32_bf16(al[p], bh[q], acc[p][q], 0, 0, 0);
            }
        __syncthreads();
    }

    #pragma unroll
    for (int p = 0; p < 4; p++)
        #pragma unroll
        for (int q = 0; q < 2; q++) {
            int gcol = col0 + wc * 32 + q * 16 + m;
            #pragma unroll
            for (int r = 0; r < 4; r++) {
                int grow = row0 + wr * 64 + p * 16 + quad * 4 + r;
                C[(size_t)grow * ldc + gcol] = acc[p][q][r];
            }
        }
}

// ---------------------------------------------------------------------------
// Phase: x_proj GEMM (fp32) with depthwise conv+silu fused into A-staging.
// 512 virtual (by,z) blocks as two half-blocks per mega-block.
// ---------------------------------------------------------------------------
__device__ __forceinline__ void xp_phase(
    const float* __restrict__ XZ, const float* __restrict__ cw,
    const float* __restrict__ cb, float* __restrict__ XCb,
    const float* __restrict__ W, int step,
    float* __restrict__ Cc, size_t partStride, Smem& sm, int blk, int tid)
{
    constexpr int Nout = 48, Ktot = DI;
    const int half = tid >> 8;
    const int t    = tid & 255;
    const int vb   = blk * 2 + half;        // 0..511
    const int by   = vb & 63, bz = vb >> 6;
    float (*As)[68] = sm.xp.As[half];
    float (*Bs)[68] = sm.xp.Bs[half];

    const int row0 = by * 64;
    const int g    = row0 >> 11;
    const int lay  = g * 2 + step;
    const float* Wg = W + (size_t)lay * Nout * Ktot;
    const int tx = t & 15, ty = t >> 4;
    const int Kc    = Ktot / SKX;           // 64
    const int kbase = bz * Kc;
    const int NT    = Kc / 16;              // 4

    const int sr = t >> 2;
    const int sk = (t & 3) * 4;
    const int gr = row0 + sr;
    const int l  = gr & 1023;
    const bool bok = (sr < Nout);

    float4 pa, pb;
    auto loadT = [&](int kt) {
        const int ch = kbase + kt * 16 + sk;
        const float* wb = cw + ((size_t)lay * 512 + ch) * 4;
        float4 w0 = *(const float4*)&wb[0];
        float4 w1 = *(const float4*)&wb[4];
        float4 w2 = *(const float4*)&wb[8];
        float4 w3 = *(const float4*)&wb[12];
        float4 acc = *(const float4*)&cb[(size_t)lay * 512 + ch];
        #pragma unroll
        for (int k = 0; k < 4; k++) {
            if (l - 3 + k < 0) continue;
            float4 xv = *(const float4*)&XZ[(size_t)(gr - 3 + k) * 1024 + ch];
            acc.x += (&w0.x)[k] * xv.x; acc.y += (&w1.x)[k] * xv.y;
            acc.z += (&w2.x)[k] * xv.z; acc.w += (&w3.x)[k] * xv.w;
        }
        acc.x = silu_f(acc.x); acc.y = silu_f(acc.y);
        acc.z = silu_f(acc.z); acc.w = silu_f(acc.w);
        pa = acc;
        *(float4*)&XCb[(size_t)gr * 512 + ch] = acc;     // side product
        pb = bok ? *(const float4*)&Wg[(size_t)sr * Ktot + kbase + kt * 16 + sk]
                 : make_float4(0.f, 0.f, 0.f, 0.f);
    };

    float acc[4][4] = {};
    loadT(0);

    for (int kt = 0; kt < NT; kt++) {
        As[sk + 0][sr] = pa.x; As[sk + 1][sr] = pa.y;
        As[sk + 2][sr] = pa.z; As[sk + 3][sr] = pa.w;
        Bs[sk + 0][sr] = pb.x; Bs[sk + 1][sr] = pb.y;
        Bs[sk + 2][sr] = pb.z; Bs[sk + 3][sr] = pb.w;
        __syncthreads();
        if (kt + 1 < NT) loadT(kt + 1);
        #pragma unroll
        for (int kk = 0; kk < 16; kk++) {
            float4 a = *(const float4*)&As[kk][ty * 4];
            float4 b = *(const float4*)&Bs[kk][tx * 4];
            float av[4] = {a.x, a.y, a.z, a.w};
            float bv[4] = {b.x, b.y, b.z, b.w};
            #pragma unroll
            for (int i = 0; i < 4; i++)
                #pragma unroll
                for (int j = 0; j < 4; j++) acc[i][j] += av[i] * bv[j];
        }
        __syncthreads();
    }

    float* Cz = Cc + (size_t)bz * partStride;
    const int col = tx * 4;
    if (col < Nout) {
        #pragma unroll
        for (int i = 0; i < 4; i++) {
            int r = row0 + ty * 4 + i;
            *(float4*)&Cz[(size_t)r * 48 + col] =
                make_float4(acc[i][0], acc[i][1], acc[i][2], acc[i][3]);
        }
    }
}

// ---------------------------------------------------------------------------
// Phase: scanA. Sums SKX slabs into LDS dbl (persists to scanB - no DBLc),
// stages xc and dt into LDS for scanB, computes per-chunk (Aprod, Hend).
// ---------------------------------------------------------------------------
__device__ __forceinline__ void sa_phase(
    const float* __restrict__ XCb, const float* __restrict__ Pdbl,
    const float* __restrict__ A_log, const float* __restrict__ Wdt,
    const float* __restrict__ bdt,
    float* __restrict__ Aprod, float* __restrict__ Hend, int step,
    Smem& sm, int blk, int tid)
{
    const int c  = blk & (CH - 1);
    const int gb = blk >> 6;
    const int g  = gb >> 1;
    const int lay = g * 2 + step;
    const int d  = tid;
    const int r0 = gb * L + c * CL;

    for (int id = tid; id < CL * 48; id += NTHR) {
        int rr = id / 48, cc = id - rr * 48;
        size_t o = (size_t)(r0 + rr) * 48 + cc;
        float v = 0.f;
        #pragma unroll
        for (int s = 0; s < SKX; s++) v += Pdbl[(size_t)s * (RTOT * 48) + o];
        sm.sc.dbl[rr][cc] = v;
    }
    #pragma unroll
    for (int tt = 0; tt < CL; tt++)
        sm.sc.xcs[tt][d] = XCb[(size_t)(r0 + tt) * DI + d];

    float wdt[16];
    const float* wrow = Wdt + ((size_t)lay * DI + d) * DR;
    #pragma unroll
    for (int k = 0; k < 16; k += 4) {
        float4 v = *(const float4*)&wrow[k];
        wdt[k] = v.x; wdt[k + 1] = v.y; wdt[k + 2] = v.z; wdt[k + 3] = v.w;
    }
    float bias = bdt[(size_t)lay * DI + d];

    float a[DS], h[DS], ap[DS];
    const float* al = A_log + ((size_t)lay * DI + d) * DS;
    #pragma unroll
    for (int s = 0; s < DS; s++) { a[s] = -__expf(al[s]); h[s] = 0.f; ap[s] = 1.f; }
    __syncthreads();

    for (int tt = 0; tt < CL; tt++) {
        float dtr = bias;
        #pragma unroll
        for (int k = 0; k < 16; k++) dtr += sm.sc.dbl[tt][k] * wdt[k];
        float dt = softplus_f(dtr);
        sm.sc.dts[tt][d] = dt;                 // carried to scanB
        float dx = dt * sm.sc.xcs[tt][d];
        #pragma unroll
        for (int s = 0; s < DS; s++) {
            float da = __expf(dt * a[s]);
            h[s] = da * h[s] + dx * sm.sc.dbl[tt][16 + s];
            ap[s] *= da;
        }
    }
    size_t base = ((size_t)(gb * DI + d) * CH + c) * DS;
    #pragma unroll
    for (int q = 0; q < 4; q++) {
        *(float4*)&Aprod[base + q * 4] = make_float4(ap[q*4], ap[q*4+1], ap[q*4+2], ap[q*4+3]);
        *(float4*)&Hend [base + q * 4] = make_float4(h[q*4],  h[q*4+1],  h[q*4+2],  h[q*4+3]);
    }
}

// ---------------------------------------------------------------------------
// Phase: combine - serial exclusive scan over CH chunks per (gb,d,s) lane.
// Uses 32768 of the 131072 grid threads; the rest fall through to grid.sync.
// ---------------------------------------------------------------------------
__device__ __forceinline__ void comb_phase(
    const float* __restrict__ Aprod, const float* __restrict__ Hend,
    float* __restrict__ Hinit, int gid)
{
    if (gid < G * BB * DI * DS) {
        int s  = gid & 15;
        int gd = gid >> 4;
        size_t base = (size_t)gd * CH * DS + s;
        float h = 0.f;
        for (int c0 = 0; c0 < CH; c0 += 8) {
            float ap[8], e[8];
            #pragma unroll
            for (int j = 0; j < 8; j++) {
                size_t o = base + (size_t)(c0 + j) * DS;
                ap[j] = Aprod[o]; e[j] = Hend[o];
            }
            #pragma unroll
            for (int j = 0; j < 8; j++) {
                Hinit[base + (size_t)(c0 + j) * DS] = h;
                h = ap[j] * h + e[j];
            }
        }
    }
}

// ---------------------------------------------------------------------------
// Phase: scanB + fused out_proj. dbl/xc/dt come from LDS (persisted from
// scanA - same block = same chunk). OUTMODE 0: Pout bf16 hi/lo; 1: scatter.
// ---------------------------------------------------------------------------
template<int OUTMODE>
__device__ __forceinline__ void sb_phase(
    const float* __restrict__ XZ, const float* __restrict__ A_log,
    const float* __restrict__ Dp, const float* __restrict__ Hinit,
    const short* __restrict__ Woh, const short* __restrict__ Wol,
    float* __restrict__ Cout, short* __restrict__ Ph, short* __restrict__ Pl,
    int step, Smem& sm, int blk, int tid)
{
    const int c  = blk & (CH - 1);
    const int gb = blk >> 6;
    const int g  = gb >> 1;
    const int lay = g * 2 + step;
    const int d  = tid;
    const int r0 = gb * L + c * CL;

    float zz[CL];
    #pragma unroll
    for (int tt = 0; tt < CL; tt++) zz[tt] = XZ[(size_t)(r0 + tt) * 1024 + 512 + d];

    float a[DS], h[DS];
    const float* al = A_log + ((size_t)lay * DI + d) * DS;
    size_t base = ((size_t)(gb * DI + d) * CH + c) * DS;
    #pragma unroll
    for (int q = 0; q < 4; q++) {
        float4 hv = *(const float4*)&Hinit[base + q * 4];
        h[q*4] = hv.x; h[q*4+1] = hv.y; h[q*4+2] = hv.z; h[q*4+3] = hv.w;
    }
    #pragma unroll
    for (int s = 0; s < DS; s++) a[s] = -__expf(al[s]);
    float Dv = Dp[(size_t)lay * DI + d];

    #pragma unroll
    for (int tt = 0; tt < CL; tt++) {
        float dt  = sm.sc.dts[tt][d];
        float xcv = sm.sc.xcs[tt][d];
        float dx = dt * xcv;
        float y = 0.f;
        #pragma unroll
        for (int s = 0; s < DS; s++) {
            float da = __expf(dt * a[s]);
            h[s] = da * h[s] + dx * sm.sc.dbl[tt][16 + s];
            y += h[s] * sm.sc.dbl[tt][32 + s];
        }
        y += xcv * Dv;
        y *= silu_f(zz[tt]);
        unsigned short hs = f2bf(y);
        sm.sc.Ys_hi[tt * YSTR + d] = (short)hs;
        sm.sc.Ys_lo[tt * YSTR + d] = (short)f2bf(y - bf2f(hs));
    }
    __syncthreads();

    // ---- fused out_proj epilogue: 16 rows x 256 cols, K=512 ----
    const int lane = tid & 63, wv = tid >> 6;
    const int m = lane & 15, quad = lane >> 4;
    const size_t wbase = (size_t)lay * DM * DI;

    #pragma unroll
    for (int q = 0; q < 2; q++) {
        const int coln = wv * 32 + q * 16 + m;
        const size_t wrow2 = wbase + (size_t)coln * DI;
        bh8 wh[16], wl[16];
        #pragma unroll
        for (int i = 0; i < 16; i++) {
            const int kk = i * 32 + quad * 8;
            wh[i] = *(const bh8*)&Woh[wrow2 + kk];
            wl[i] = *(const bh8*)&Wol[wrow2 + kk];
        }
        f4x acc = {};
        #pragma unroll
        for (int i = 0; i < 16; i++) {
            const int kk = i * 32 + quad * 8;
            bh8 ahv = *(bh8*)&sm.sc.Ys_hi[m * YSTR + kk];
            bh8 alv = *(bh8*)&sm.sc.Ys_lo[m * YSTR + kk];
            acc = __builtin_amdgcn_mfma_f32_16x16x32_bf16(ahv, wh[i], acc, 0, 0, 0);
            acc = __builtin_amdgcn_mfma_f32_16x16x32_bf16(ahv, wl[i], acc, 0, 0, 0);
            acc = __builtin_amdgcn_mfma_f32_16x16x32_bf16(alv, wh[i], acc, 0, 0, 0);
        }
        #pragma unroll
        for (int r = 0; r < 4; r++) {
            int tt = quad * 4 + r;
            int grow = r0 + tt;
            if (OUTMODE == 0) {
                size_t o = (size_t)grow * DM + coln;
                unsigned short hs = f2bf(acc[r]);
                Ph[o] = (short)hs;
                Pl[o] = (short)f2bf(acc[r] - bf2f(hs));
            } else {
                int b = (grow >> 10) & 1, l = grow & 1023;
                size_t dst = (g == 0)
                    ? ((size_t)(b * 1024 + l) * 512 + coln)
                    : ((size_t)(b * 1024 + (1023 - l)) * 512 + 256 + coln);
                Cout[dst] = acc[r];
            }
        }
    }
}

// ---------------------------------------------------------------------------
// The mega-kernel: entire bidirectional 2-layer pipeline in ONE cooperative
// dispatch. grid.sync() replaces the 10 inter-dispatch boundaries.
// ---------------------------------------------------------------------------
__global__ __launch_bounds__(NTHR) void mamba_mega(
    const float* __restrict__ x, const float* __restrict__ in_proj,
    const float* __restrict__ conv_w, const float* __restrict__ conv_b,
    const float* __restrict__ x_proj, const float* __restrict__ dt_proj,
    const float* __restrict__ dt_bias, const float* __restrict__ A_log,
    const float* __restrict__ Dp, const float* __restrict__ out_proj,
    float* __restrict__ out,
    float* __restrict__ XZ, float* __restrict__ XCb, float* __restrict__ Pdbl,
    float* __restrict__ Aprod, float* __restrict__ Hend, float* __restrict__ Hinit,
    short* __restrict__ Wih, short* __restrict__ Wil,
    short* __restrict__ Woh, short* __restrict__ Wol,
    short* __restrict__ Ph, short* __restrict__ Pl)
{
    cg::grid_group grid = cg::this_grid();
    __shared__ Smem sm;
    const int blk = blockIdx.x;
    const int tid = threadIdx.x;
    const int gid = blk * NTHR + tid;

    // ---- phase 0: one-time weight pre-conversion (fp32 -> bf16 hi/lo) ----
    {
        constexpr int n4a = NWIN / 4, n4b = NWOUT / 4;   // 393216 = 3*131072
        for (int i = gid; i < n4a + n4b; i += NBLK * NTHR) {
            int j = i; const float* Wsrc; short *Wh, *Wl;
            if (j < n4a) { Wsrc = in_proj; Wh = Wih; Wl = Wil; }
            else { j -= n4a; Wsrc = out_proj; Wh = Woh; Wl = Wol; }
            float4 v = *(const float4*)&Wsrc[(size_t)j * 4];
            short4 hh, ll;
            unsigned short s;
            s = f2bf(v.x); hh.x = (short)s; ll.x = (short)f2bf(v.x - bf2f(s));
            s = f2bf(v.y); hh.y = (short)s; ll.y = (short)f2bf(v.y - bf2f(s));
            s = f2bf(v.z); hh.z = (short)s; ll.z = (short)f2bf(v.z - bf2f(s));
            s = f2bf(v.w); hh.w = (short)s; ll.w = (short)f2bf(v.w - bf2f(s));
            *(short4*)&Wh[(size_t)j * 4] = hh;
            *(short4*)&Wl[(size_t)j * 4] = ll;
        }
    }
    grid.sync();

    // ===== step 0 =====
    ip_phase<1>(x, nullptr, nullptr, Wih, Wil, 0, XZ, sm, blk, tid);
    grid.sync();
    xp_phase(XZ, conv_w, conv_b, XCb, x_proj, 0, Pdbl, (size_t)RTOT * 48, sm, blk, tid);
    grid.sync();
    sa_phase(XCb, Pdbl, A_log, dt_proj, dt_bias, Aprod, Hend, 0, sm, blk, tid);
    grid.sync();
    comb_phase(Aprod, Hend, Hinit, gid);
    grid.sync();
    sb_phase<0>(XZ, A_log, Dp, Hinit, Woh, Wol, nullptr, Ph, Pl, 0, sm, blk, tid);
    grid.sync();

    // ===== step 1 =====
    ip_phase<0>(nullptr, Ph, Pl, Wih, Wil, 1, XZ, sm, blk, tid);
    grid.sync();
    xp_phase(XZ, conv_w, conv_b, XCb, x_proj, 1, Pdbl, (size_t)RTOT * 48, sm, blk, tid);
    grid.sync();
    sa_phase(XCb, Pdbl, A_log, dt_proj, dt_bias, Aprod, Hend, 1, sm, blk, tid);
    grid.sync();
    comb_phase(Aprod, Hend, Hinit, gid);
    grid.sync();
    sb_phase<1>(XZ, A_log, Dp, Hinit, Woh, Wol, out, nullptr, nullptr, 1, sm, blk, tid);
}

// ===========================================================================
// Fallback path: the previous 11-dispatch pipeline, used only if the
// cooperative launch is rejected (e.g. by graph capture).
// ===========================================================================
__global__ __launch_bounds__(256) void cvtW2(
    const float* __restrict__ Wa, short* __restrict__ Wah, short* __restrict__ Wal, int n4a,
    const float* __restrict__ Wb, short* __restrict__ Wbh, short* __restrict__ Wbl, int n4b)
{
    int i = blockIdx.x * 256 + threadIdx.x;
    const float* W; short *Wh, *Wl;
    if (i < n4a) { W = Wa; Wh = Wah; Wl = Wal; }
    else if (i < n4a + n4b) { i -= n4a; W = Wb; Wh = Wbh; Wl = Wbl; }
    else return;
    float4 v = *(const float4*)&W[(size_t)i * 4];
    short4 h, l;
    unsigned short s;
    s = f2bf(v.x); h.x = (short)s; l.x = (short)f2bf(v.x - bf2f(s));
    s = f2bf(v.y); h.y = (short)s; l.y = (short)f2bf(v.y - bf2f(s));
    s = f2bf(v.z); h.z = (short)s; l.z = (short)f2bf(v.z - bf2f(s));
    s = f2bf(v.w); h.w = (short)s; l.w = (short)f2bf(v.w - bf2f(s));
    *(short4*)&Wh[(size_t)i * 4] = h;
    *(short4*)&Wl[(size_t)i * 4] = l;
}

template<int AMAP>
__global__ __launch_bounds__(256) void mfma_inproj(
    const float* __restrict__ Ax,
    const short* __restrict__ Ah, const short* __restrict__ Al,
    const short* __restrict__ Wh, const short* __restrict__ Wl,
    int step, float* __restrict__ C)
{
    constexpr int BM = 128, Ktot = DM, Nout = 2 * DI, ldc = 1024;
    __shared__ short As_hi[BM * 40];
    __shared__ short As_lo[BM * 40];
    __shared__ short Bs_hi[64 * 40];
    __shared__ short Bs_lo[64 * 40];

    const int row0 = blockIdx.y * BM;
    const int col0 = blockIdx.x * 64;
    const int g    = row0 >> 11;
    const int lay  = g * 2 + step;
    const short* Whg = Wh + (size_t)lay * Nout * Ktot;
    const short* Wlg = Wl + (size_t)lay * Nout * Ktot;
    const int t    = threadIdx.x;
    const int lane = t & 63, wv = t >> 6;
    const int m = lane & 15, quad = lane >> 4;
    const int wr = wv >> 1, wc = wv & 1;
    const int NT = Ktot / 32;

    float4 pa[4];
    short4 pah[4], pal[4], pbh[2], pbl[2];
    auto loadT = [&](int kt) {
        const int kb = kt * 32;
        #pragma unroll
        for (int i = 0; i < 4; i++) {
            int id = t + 256 * i;
            int row = id >> 3, kq = id & 7;
            if (AMAP == 1) {
                int gr = row0 + row;
                int gg = gr >> 11, b = (gr >> 10) & 1, l = gr & 1023;
                int sl = gg ? (1023 - l) : l;
                pa[i] = *(const float4*)&Ax[(size_t)(b * 1024 + sl) * Ktot + kb + kq * 4];
            } else {
                size_t o = (size_t)(row0 + row) * Ktot + kb + kq * 4;
                pah[i] = *(const short4*)&Ah[o];
                pal[i] = *(const short4*)&Al[o];
            }
        }
        #pragma unroll
        for (int i = 0; i < 2; i++) {
            int id = t + 256 * i;
            int row = id >> 3, kq = id & 7;
            size_t o = (size_t)(col0 + row) * Ktot + kb + kq * 4;
            pbh[i] = *(const short4*)&Whg[o];
            pbl[i] = *(const short4*)&Wlg[o];
        }
    };

    f4x acc[4][2] = {};
    loadT(0);

    for (int kt = 0; kt < NT; kt++) {
        #pragma unroll
        for (int i = 0; i < 4; i++) {
            int id = t + 256 * i;
            int row = id >> 3, kq = id & 7;
            if (AMAP == 1) {
                float4 v = pa[i];
                short4 h, l;
                unsigned short s;
                s = f2bf(v.x); h.x = (short)s; l.x = (short)f2bf(v.x - bf2f(s));
                s = f2bf(v.y); h.y = (short)s; l.y = (short)f2bf(v.y - bf2f(s));
                s = f2bf(v.z); h.z = (short)s; l.z = (short)f2bf(v.z - bf2f(s));
                s = f2bf(v.w); h.w = (short)s; l.w = (short)f2bf(v.w - bf2f(s));
                *(short4*)&As_hi[row * 40 + kq * 4] = h;
                *(short4*)&As_lo[row * 40 + kq * 4] = l;
            } else {
                *(short4*)&As_hi[row * 40 + kq * 4] = pah[i];
                *(short4*)&As_lo[row * 40 + kq * 4] = pal[i];
            }
        }
        #pragma unroll
        for (int i = 0; i < 2; i++) {
            int id = t + 256 * i;
            int row = id >> 3, kq = id & 7;
            *(short4*)&Bs_hi[row * 40 + kq * 4] = pbh[i];
            *(short4*)&Bs_lo[row * 40 + kq * 4] = pbl[i];
        }
        __syncthreads();
        if (kt + 1 < NT) loadT(kt + 1);

        bh8 ah[4], al[4], bh[2], bl[2];
        #pragma unroll
        for (int p = 0; p < 4; p++) {
            int r = wr * 64 + p * 16 + m;
            ah[p] = *(bh8*)&As_hi[r * 40 + quad * 8];
            al[p] = *(bh8*)&As_lo[r * 40 + quad * 8];
        }
        #pragma unroll
        for (int q = 0; q < 2; q++) {
            int r = wc * 32 + q * 16 + m;
            bh[q] = *(bh8*)&Bs_hi[r * 40 + quad * 8];
            bl[q] = *(bh8*)&Bs_lo[r * 40 + quad * 8];
        }
        #pragma unroll
        for (int p = 0; p < 4; p++)
            #pragma unroll
            for (int q = 0; q < 2; q++) {
                acc[p][q] = __builtin_amdgcn_mfma_f32_16x16x32_bf16(ah[p], bh[q], acc[p][q], 0, 0, 0);
                acc[p][q] = __builtin_amdgcn_mfma_f32_16x16x32_bf16(ah[p], bl[q], acc[p][q], 0, 0, 0);
                acc[p][q] = __builtin_amdgcn_mfma_f32_16x16x32_bf16(al[p], bh[q], acc[p][q], 0, 0, 0);
            }
        __syncthreads();
    }

    #pragma unroll
    for (int p = 0; p < 4; p++)
        #pragma unroll
        for (int q = 0; q < 2; q++) {
            int gcol = col0 + wc * 32 + q * 16 + m;
            #pragma unroll
            for (int r = 0; r < 4; r++) {
                int grow = row0 + wr * 64 + p * 16 + quad * 4 + r;
                C[(size_t)grow * ldc + gcol] = acc[p][q][r];
            }
        }
}

template<int SPLITK>
__global__ __launch_bounds__(256) void gemm_xproj(
    const float* __restrict__ XZ, const float* __restrict__ cw,
    const float* __restrict__ cb, float* __restrict__ XCb,
    const float* __restrict__ W, int step,
    float* __restrict__ C, size_t partStride)
{
    constexpr int Nout = 48, Ktot = DI;
    __shared__ float As[16][68];
    __shared__ float Bs[16][68];

    const int row0 = blockIdx.y * 64;
    const int g    = row0 >> 11;
    const int lay  = g * 2 + step;
    const float* Wg = W + (size_t)lay * Nout * Ktot;
    const int t  = threadIdx.x;
    const int tx = t & 15, ty = t >> 4;
    const int Kc    = Ktot / SPLITK;
    const int kbase = blockIdx.z * Kc;
    const int NT    = Kc / 16;

    const int sr = t >> 2;
    const int sk = (t & 3) * 4;
    const int gr = row0 + sr;
    const int l  = gr & 1023;
    const bool bok = (sr < Nout);

    float4 pa, pb;
    auto loadT = [&](int kt) {
        const int ch = kbase + kt * 16 + sk;
        const float* wb = cw + ((size_t)lay * 512 + ch) * 4;
        float4 w0 = *(const float4*)&wb[0];
        float4 w1 = *(const float4*)&wb[4];
        float4 w2 = *(const float4*)&wb[8];
        float4 w3 = *(const float4*)&wb[12];
        float4 acc = *(const float4*)&cb[(size_t)lay * 512 + ch];
        #pragma unroll
        for (int k = 0; k < 4; k++) {
            if (l - 3 + k < 0) continue;
            float4 xv = *(const float4*)&XZ[(size_t)(gr - 3 + k) * 1024 + ch];
            acc.x += (&w0.x)[k] * xv.x; acc.y += (&w1.x)[k] * xv.y;
            acc.z += (&w2.x)[k] * xv.z; acc.w += (&w3.x)[k] * xv.w;
        }
        acc.x = silu_f(acc.x); acc.y = silu_f(acc.y);
        acc.z = silu_f(acc.z); acc.w = silu_f(acc.w);
        pa = acc;
        *(float4*)&XCb[(size_t)gr * 512 + ch] = acc;
        pb = bok ? *(const float4*)&Wg[(size_t)sr * Ktot + kbase + kt * 16 + sk]
                 : make_float4(0.f, 0.f, 0.f, 0.f);
    };

    float acc[4][4] = {};
    loadT(0);

    for (int kt = 0; kt < NT; kt++) {
        As[sk + 0][sr] = pa.x; As[sk + 1][sr] = pa.y;
        As[sk + 2][sr] = pa.z; As[sk + 3][sr] = pa.w;
        Bs[sk + 0][sr] = pb.x; Bs[sk + 1][sr] = pb.y;
        Bs[sk + 2][sr] = pb.z; Bs[sk + 3][sr] = pb.w;
        __syncthreads();
        if (kt + 1 < NT) loadT(kt + 1);
        #pragma unroll
        for (int kk = 0; kk < 16; kk++) {
            float4 a = *(const float4*)&As[kk][ty * 4];
            float4 b = *(const float4*)&Bs[kk][tx * 4];
            float av[4] = {a.x, a.y, a.z, a.w};
            float bv[4] = {b.x, b.y, b.z, b.w};
            #pragma unroll
            for (int i = 0; i < 4; i++)
                #pragma unroll
                for (int j = 0; j < 4; j++) acc[i][j] += av[i] * bv[j];
        }
        __syncthreads();
    }

    float* Cz = C + (size_t)blockIdx.z * partStride;
    const int col = tx * 4;
    if (col < Nout) {
        #pragma unroll
        for (int i = 0; i < 4; i++) {
            int r = row0 + ty * 4 + i;
            *(float4*)&Cz[(size_t)r * 48 + col] =
                make_float4(acc[i][0], acc[i][1], acc[i][2], acc[i][3]);
        }
    }
}

__global__ __launch_bounds__(512) void scanA(
    const float* __restrict__ XCb, const float* __restrict__ Pdbl,
    const float* __restrict__ A_log, const float* __restrict__ Wdt,
    const float* __restrict__ bdt, float* __restrict__ DBLc,
    float* __restrict__ Aprod, float* __restrict__ Hend, int step)
{
    __shared__ float dbl[CL][48];
    int blk = blockIdx.x;
    int c  = blk & (CH - 1);
    int gb = blk >> 6;
    int g  = gb >> 1;
    int lay = g * 2 + step;
    int d = threadIdx.x;
    int r0 = gb * L + c * CL;

    for (int id = threadIdx.x; id < CL * 48; id += 512) {
        int rr = id / 48, cc = id - rr * 48;
        size_t o = (size_t)(r0 + rr) * 48 + cc;
        float v = 0.f;
        #pragma unroll
        for (int s = 0; s < SKX; s++) v += Pdbl[(size_t)s * (RTOT * 48) + o];
        dbl[rr][cc] = v;
        DBLc[o] = v;
    }

    float wdt[16];
    const float* wrow = Wdt + ((size_t)lay * DI + d) * DR;
    #pragma unroll
    for (int k = 0; k < 16; k += 4) {
        float4 v = *(const float4*)&wrow[k];
        wdt[k] = v.x; wdt[k + 1] = v.y; wdt[k + 2] = v.z; wdt[k + 3] = v.w;
    }
    float bias = bdt[(size_t)lay * DI + d];

    float a[DS], h[DS], ap[DS];
    const float* al = A_log + ((size_t)lay * DI + d) * DS;
    #pragma unroll
    for (int s = 0; s < DS; s++) { a[s] = -__expf(al[s]); h[s] = 0.f; ap[s] = 1.f; }
    float xc_next = XCb[(size_t)r0 * DI + d];
    __syncthreads();

    for (int tt = 0; tt < CL; tt++) {
        float xcv = xc_next;
        if (tt + 1 < CL) xc_next = XCb[(size_t)(r0 + tt + 1) * DI + d];
        float dtr = bias;
        #pragma unroll
        for (int k = 0; k < 16; k++) dtr += dbl[tt][k] * wdt[k];
        float dt = softplus_f(dtr);
        float dx = dt * xcv;
        #pragma unroll
        for (int s = 0; s < DS; s++) {
            float da = __expf(dt * a[s]);
            h[s] = da * h[s] + dx * dbl[tt][16 + s];
            ap[s] *= da;
        }
    }
    size_t base = ((size_t)(gb * DI + d) * CH + c) * DS;
    #pragma unroll
    for (int q = 0; q < 4; q++) {
        *(float4*)&Aprod[base + q * 4] = make_float4(ap[q*4], ap[q*4+1], ap[q*4+2], ap[q*4+3]);
        *(float4*)&Hend [base + q * 4] = make_float4(h[q*4],  h[q*4+1],  h[q*4+2],  h[q*4+3]);
    }
}

__global__ __launch_bounds__(256) void scanCombine(
    const float* __restrict__ Aprod, const float* __restrict__ Hend,
    float* __restrict__ Hinit)
{
    int idx = blockIdx.x * 256 + threadIdx.x;
    int s  = idx & 15;
    int gd = idx >> 4;
    size_t base = (size_t)gd * CH * DS + s;
    float h = 0.f;
    for (int c0 = 0; c0 < CH; c0 += 8) {
        float ap[8], e[8];
        #pragma unroll
        for (int j = 0; j < 8; j++) {
            size_t o = base + (size_t)(c0 + j) * DS;
            ap[j] = Aprod[o]; e[j] = Hend[o];
        }
        #pragma unroll
        for (int j = 0; j < 8; j++) {
            Hinit[base + (size_t)(c0 + j) * DS] = h;
            h = ap[j] * h + e[j];
        }
    }
}

template<int OUTMODE>
__global__ __launch_bounds__(512) void scanB_fused(
    const float* __restrict__ XCb, const float* __restrict__ DBLc,
    const float* __restrict__ XZ, const float* __restrict__ A_log,
    const float* __restrict__ Wdt, const float* __restrict__ bdt,
    const float* __restrict__ Dp, const float* __restrict__ Hinit,
    const short* __restrict__ Woh, const short* __restrict__ Wol,
    float* __restrict__ Cout, short* __restrict__ Ph, short* __restrict__ Pl,
    int step)
{
    __shared__ float dbl[CL][48];
    __shared__ short Ys_hi[CL * YSTR];
    __shared__ short Ys_lo[CL * YSTR];
    int blk = blockIdx.x;
    int c  = blk & (CH - 1);
    int gb = blk >> 6;
    int g  = gb >> 1;
    int lay = g * 2 + step;
    int d = threadIdx.x;
    int r0 = gb * L + c * CL;

    for (int id = threadIdx.x; id < CL * 48; id += 512) {
        int rr = id / 48, cc = id - rr * 48;
        dbl[rr][cc] = DBLc[(size_t)(r0 + rr) * 48 + cc];
    }

    float xc[CL], zz[CL];
    #pragma unroll
    for (int tt = 0; tt < CL; tt++) xc[tt] = XCb[(size_t)(r0 + tt) * DI + d];
    #pragma unroll
    for (int tt = 0; tt < CL; tt++) zz[tt] = XZ[(size_t)(r0 + tt) * 1024 + 512 + d];

    float wdt[16];
    const float* wrow = Wdt + ((size_t)lay * DI + d) * DR;
    #pragma unroll
    for (int k = 0; k < 16; k += 4) {
        float4 v = *(const float4*)&wrow[k];
        wdt[k] = v.x; wdt[k + 1] = v.y; wdt[k + 2] = v.z; wdt[k + 3] = v.w;
    }
    float bias = bdt[(size_t)lay * DI + d];

    float a[DS], h[DS];
    const float* al = A_log + ((size_t)lay * DI + d) * DS;
    size_t base = ((size_t)(gb * DI + d) * CH + c) * DS;
    #pragma unroll
    for (int q = 0; q < 4; q++) {
        float4 hv = *(const float4*)&Hinit[base + q * 4];
        h[q*4] = hv.x; h[q*4+1] = hv.y; h[q*4+2] = hv.z; h[q*4+3] = hv.w;
    }
    #pragma unroll
    for (int s = 0; s < DS; s++) a[s] = -__expf(al[s]);
    float Dv = Dp[(size_t)lay * DI + d];
    __syncthreads();

    #pragma unroll
    for (int tt = 0; tt < CL; tt++) {
        float dtr = bias;
        #pragma unroll
        for (int k = 0; k < 16; k++) dtr += dbl[tt][k] * wdt[k];
        float dt = softplus_f(dtr);
        float dx = dt * xc[tt];
        float y = 0.f;
        #pragma unroll
        for (int s = 0; s < DS; s++) {
            float da = __expf(dt * a[s]);
            h[s] = da * h[s] + dx * dbl[tt][16 + s];
            y += h[s] * dbl[tt][32 + s];
        }
        y += xc[tt] * Dv;
        y *= silu_f(zz[tt]);
        unsigned short hs = f2bf(y);
        Ys_hi[tt * YSTR + d] = (short)hs;
        Ys_lo[tt * YSTR + d] = (short)f2bf(y - bf2f(hs));
    }
    __syncthreads();

    const int lane = threadIdx.x & 63, wv = threadIdx.x >> 6;
    const int m = lane & 15, quad = lane >> 4;
    const size_t wbase = (size_t)lay * DM * DI;

    #pragma unroll
    for (int q = 0; q < 2; q++) {
        const int coln = wv * 32 + q * 16 + m;
        const size_t wrow2 = wbase + (size_t)coln * DI;
        bh8 wh[16], wl[16];
        #pragma unroll
        for (int i = 0; i < 16; i++) {
            const int kk = i * 32 + quad * 8;
            wh[i] = *(const bh8*)&Woh[wrow2 + kk];
            wl[i] = *(const bh8*)&Wol[wrow2 + kk];
        }
        f4x acc = {};
        #pragma unroll
        for (int i = 0; i < 16; i++) {
            const int kk = i * 32 + quad * 8;
            bh8 ahv = *(bh8*)&Ys_hi[m * YSTR + kk];
            bh8 alv = *(bh8*)&Ys_lo[m * YSTR + kk];
            acc = __builtin_amdgcn_mfma_f32_16x16x32_bf16(ahv, wh[i], acc, 0, 0, 0);
            acc = __builtin_amdgcn_mfma_f32_16x16x32_bf16(ahv, wl[i], acc, 0, 0, 0);
            acc = __builtin_amdgcn_mfma_f32_16x16x32_bf16(alv, wh[i], acc, 0, 0, 0);
        }
        #pragma unroll
        for (int r = 0; r < 4; r++) {
            int tt = quad * 4 + r;
            int grow = r0 + tt;
            if (OUTMODE == 0) {
                size_t o = (size_t)grow * DM + coln;
                unsigned short hs = f2bf(acc[r]);
                Ph[o] = (short)hs;
                Pl[o] = (short)f2bf(acc[r] - bf2f(hs));
            } else {
                int b = (grow >> 10) & 1, l = grow & 1023;
                size_t dst = (g == 0)
                    ? ((size_t)(b * 1024 + l) * 512 + coln)
                    : ((size_t)(b * 1024 + (1023 - l)) * 512 + 256 + coln);
                Cout[dst] = acc[r];
            }
        }
    }
}

extern "C" void kernel_launch(void* const* d_in, const int* in_sizes, int n_in,
                              void* d_out, int out_size, void* d_ws, size_t ws_size,
                              hipStream_t stream)
{
    const float* x        = (const float*)d_in[0];
    const float* in_proj  = (const float*)d_in[1];
    const float* conv_w   = (const float*)d_in[2];
    const float* conv_b   = (const float*)d_in[3];
    const float* x_proj   = (const float*)d_in[4];
    const float* dt_proj  = (const float*)d_in[5];
    const float* dt_bias  = (const float*)d_in[6];
    const float* A_log    = (const float*)d_in[7];
    const float* Dp       = (const float*)d_in[8];
    const float* out_proj = (const float*)d_in[9];
    float* out = (float*)d_out;

    float* w = (float*)d_ws;
    size_t o = 0;
    float* XZ    = w + o; o += (size_t)RTOT * 1024;
    float* XCb   = w + o; o += (size_t)RTOT * DI;
    float* Pdbl  = w + o; o += (size_t)SKX * RTOT * 48;
    float* DBLc  = w + o; o += (size_t)RTOT * 48;          // fallback path only
    float* Aprod = w + o; o += (size_t)G * BB * DI * CH * DS;
    float* Hend  = w + o; o += (size_t)G * BB * DI * CH * DS;
    float* Hinit = w + o; o += (size_t)G * BB * DI * CH * DS;
    short* Wih   = (short*)(w + o); o += NWIN / 2;
    short* Wil   = (short*)(w + o); o += NWIN / 2;
    short* Woh   = (short*)(w + o); o += NWOUT / 2;
    short* Wol   = (short*)(w + o); o += NWOUT / 2;
    short* Ph    = (short*)(w + o); o += (size_t)RTOT * DM / 2;
    short* Pl    = (short*)(w + o); o += (size_t)RTOT * DM / 2;
    (void)ws_size; (void)in_sizes; (void)n_in; (void)out_size;

    // ---- preferred path: ONE cooperative dispatch for the whole pipeline ----
    void* kargs[] = {
        (void*)&x, (void*)&in_proj, (void*)&conv_w, (void*)&conv_b,
        (void*)&x_proj, (void*)&dt_proj, (void*)&dt_bias, (void*)&A_log,
        (void*)&Dp, (void*)&out_proj, (void*)&out,
        (void*)&XZ, (void*)&XCb, (void*)&Pdbl,
        (void*)&Aprod, (void*)&Hend, (void*)&Hinit,
        (void*)&Wih, (void*)&Wil, (void*)&Woh, (void*)&Wol,
        (void*)&Ph, (void*)&Pl };
    hipError_t err = hipLaunchCooperativeKernel(
        reinterpret_cast<void*>(mamba_mega), dim3(NBLK), dim3(NTHR),
        kargs, 0, stream);
    if (err == hipSuccess) return;
    (void)hipGetLastError();   // clear error state; fall back to split pipeline

    // ---- fallback: previous 11-dispatch pipeline ----
    {
        int n4a = NWIN / 4, n4b = NWOUT / 4;
        cvtW2<<<(n4a + n4b + 255) / 256, 256, 0, stream>>>(
            in_proj, Wih, Wil, n4a, out_proj, Woh, Wol, n4b);
    }
    for (int step = 0; step < 2; step++) {
        if (step == 0)
            mfma_inproj<1><<<dim3(16, 32), 256, 0, stream>>>(
                x, nullptr, nullptr, Wih, Wil, 0, XZ);
        else
            mfma_inproj<0><<<dim3(16, 32), 256, 0, stream>>>(
                nullptr, Ph, Pl, Wih, Wil, 1, XZ);

        gemm_xproj<SKX><<<dim3(1, 64, SKX), 256, 0, stream>>>(
            XZ, conv_w, conv_b, XCb, x_proj, step, Pdbl, (size_t)RTOT * 48);

        scanA<<<G * BB * CH, 512, 0, stream>>>(
            XCb, Pdbl, A_log, dt_proj, dt_bias, DBLc, Aprod, Hend, step);
        scanCombine<<<(G * BB * DI * DS) / 256, 256, 0, stream>>>(Aprod, Hend, Hinit);
        if (step == 0)
            scanB_fused<0><<<G * BB * CH, 512, 0, stream>>>(
                XCb, DBLc, XZ, A_log, dt_proj, dt_bias, Dp, Hinit,
                Woh, Wol, nullptr, Ph, Pl, 0);
        else
            scanB_fused<1><<<G * BB * CH, 512, 0, stream>>>(
                XCb, DBLc, XZ, A_log, dt_proj, dt_bias, Dp, Hinit,
                Woh, Wol, out, nullptr, nullptr, 1);
    }
}

// Round 2
// 223.566 us; speedup vs baseline: 2.6758x; 2.6758x over previous
//
#include <hip/hip_runtime.h>
#include <math.h>

#define G 2
#define BB 2
#define L 1024
#define DM 256
#define DI 512
#define DS 16
#define DR 16
#define CH 64              // chunks per sequence
#define CL 16              // L / CH
#define RTOT (G*BB*L)      // 4096 rows per layer-step
#define YSTR 520           // Ys LDS row stride (shorts)
#define XSTR 520           // xc LDS row stride (shorts)

#define NWIN  (4 * 2 * DI * DM)   // in_proj elements (4 layers)
#define NWOUT (4 * DM * DI)       // out_proj elements
#define NWX   (4 * 48 * DI)       // x_proj elements (4 layers)

typedef short bh8 __attribute__((ext_vector_type(8)));
typedef float f4x __attribute__((ext_vector_type(4)));

__device__ __forceinline__ float silu_f(float x) { return x / (1.f + __expf(-x)); }
__device__ __forceinline__ float softplus_f(float x) {
    return (x > 20.f) ? x : __logf(1.f + __expf(x));
}

__device__ __forceinline__ unsigned short f2bf(float f) {
    unsigned u = __float_as_uint(f);
    unsigned r = u + 0x7FFFu + ((u >> 16) & 1u);
    return (unsigned short)(r >> 16);
}
__device__ __forceinline__ float bf2f(unsigned short s) {
    return __uint_as_float(((unsigned)s) << 16);
}

// ---------------------------------------------------------------------------
// One-time weight pre-conversion (in_proj, out_proj, x_proj in ONE dispatch):
// fp32 -> (bf16 hi, bf16 lo) pairs.
// ---------------------------------------------------------------------------
__global__ __launch_bounds__(256) void cvtW3(
    const float* __restrict__ Wa, short* __restrict__ Wah, short* __restrict__ Wal, int n4a,
    const float* __restrict__ Wb, short* __restrict__ Wbh, short* __restrict__ Wbl, int n4b,
    const float* __restrict__ Wc, short* __restrict__ Wch, short* __restrict__ Wcl, int n4c)
{
    int i = blockIdx.x * 256 + threadIdx.x;
    const float* W; short *Wh, *Wl;
    if (i < n4a) { W = Wa; Wh = Wah; Wl = Wal; }
    else if (i < n4a + n4b) { i -= n4a; W = Wb; Wh = Wbh; Wl = Wbl; }
    else if (i < n4a + n4b + n4c) { i -= n4a + n4b; W = Wc; Wh = Wch; Wl = Wcl; }
    else return;
    float4 v = *(const float4*)&W[(size_t)i * 4];
    short4 h, l;
    unsigned short s;
    s = f2bf(v.x); h.x = (short)s; l.x = (short)f2bf(v.x - bf2f(s));
    s = f2bf(v.y); h.y = (short)s; l.y = (short)f2bf(v.y - bf2f(s));
    s = f2bf(v.z); h.z = (short)s; l.z = (short)f2bf(v.z - bf2f(s));
    s = f2bf(v.w); h.w = (short)s; l.w = (short)f2bf(v.w - bf2f(s));
    *(short4*)&Wh[(size_t)i * 4] = h;
    *(short4*)&Wl[(size_t)i * 4] = l;
}

// ---------------------------------------------------------------------------
// in_proj MFMA GEMM (3xbf16). BM=128, N=1024, K=256.  (baseline, unchanged)
// AMAP 1: A = x (fp32) with g-dependent time reversal (step 0).
// AMAP 0: A = Pout as pre-split bf16 hi/lo (step 1) - cvt-free staging.
// ---------------------------------------------------------------------------
template<int AMAP>
__global__ __launch_bounds__(256) void mfma_inproj(
    const float* __restrict__ Ax,
    const short* __restrict__ Ah, const short* __restrict__ Al,
    const short* __restrict__ Wh, const short* __restrict__ Wl,
    int step, float* __restrict__ C)
{
    constexpr int BM = 128, Ktot = DM, Nout = 2 * DI, ldc = 1024;
    __shared__ short As_hi[BM * 40];
    __shared__ short As_lo[BM * 40];
    __shared__ short Bs_hi[64 * 40];
    __shared__ short Bs_lo[64 * 40];

    const int row0 = blockIdx.y * BM;
    const int col0 = blockIdx.x * 64;
    const int g    = row0 >> 11;
    const int lay  = g * 2 + step;
    const short* Whg = Wh + (size_t)lay * Nout * Ktot;
    const short* Wlg = Wl + (size_t)lay * Nout * Ktot;
    const int t    = threadIdx.x;
    const int lane = t & 63, wv = t >> 6;
    const int m = lane & 15, quad = lane >> 4;
    const int wr = wv >> 1, wc = wv & 1;
    const int NT = Ktot / 32;     // 8

    float4 pa[4];
    short4 pah[4], pal[4], pbh[2], pbl[2];
    auto loadT = [&](int kt) {
        const int kb = kt * 32;
        #pragma unroll
        for (int i = 0; i < 4; i++) {
            int id = t + 256 * i;
            int row = id >> 3, kq = id & 7;
            if (AMAP == 1) {
                int gr = row0 + row;
                int gg = gr >> 11, b = (gr >> 10) & 1, l = gr & 1023;
                int sl = gg ? (1023 - l) : l;
                pa[i] = *(const float4*)&Ax[(size_t)(b * 1024 + sl) * Ktot + kb + kq * 4];
            } else {
                size_t o = (size_t)(row0 + row) * Ktot + kb + kq * 4;
                pah[i] = *(const short4*)&Ah[o];
                pal[i] = *(const short4*)&Al[o];
            }
        }
        #pragma unroll
        for (int i = 0; i < 2; i++) {
            int id = t + 256 * i;
            int row = id >> 3, kq = id & 7;
            size_t o = (size_t)(col0 + row) * Ktot + kb + kq * 4;
            pbh[i] = *(const short4*)&Whg[o];
            pbl[i] = *(const short4*)&Wlg[o];
        }
    };

    f4x acc[4][2] = {};
    loadT(0);

    for (int kt = 0; kt < NT; kt++) {
        #pragma unroll
        for (int i = 0; i < 4; i++) {
            int id = t + 256 * i;
            int row = id >> 3, kq = id & 7;
            if (AMAP == 1) {
                float4 v = pa[i];
                short4 h, l;
                unsigned short s;
                s = f2bf(v.x); h.x = (short)s; l.x = (short)f2bf(v.x - bf2f(s));
                s = f2bf(v.y); h.y = (short)s; l.y = (short)f2bf(v.y - bf2f(s));
                s = f2bf(v.z); h.z = (short)s; l.z = (short)f2bf(v.z - bf2f(s));
                s = f2bf(v.w); h.w = (short)s; l.w = (short)f2bf(v.w - bf2f(s));
                *(short4*)&As_hi[row * 40 + kq * 4] = h;
                *(short4*)&As_lo[row * 40 + kq * 4] = l;
            } else {
                *(short4*)&As_hi[row * 40 + kq * 4] = pah[i];
                *(short4*)&As_lo[row * 40 + kq * 4] = pal[i];
            }
        }
        #pragma unroll
        for (int i = 0; i < 2; i++) {
            int id = t + 256 * i;
            int row = id >> 3, kq = id & 7;
            *(short4*)&Bs_hi[row * 40 + kq * 4] = pbh[i];
            *(short4*)&Bs_lo[row * 40 + kq * 4] = pbl[i];
        }
        __syncthreads();
        if (kt + 1 < NT) loadT(kt + 1);

        bh8 ah[4], al[4], bh[2], bl[2];
        #pragma unroll
        for (int p = 0; p < 4; p++) {
            int r = wr * 64 + p * 16 + m;
            ah[p] = *(bh8*)&As_hi[r * 40 + quad * 8];
            al[p] = *(bh8*)&As_lo[r * 40 + quad * 8];
        }
        #pragma unroll
        for (int q = 0; q < 2; q++) {
            int r = wc * 32 + q * 16 + m;
            bh[q] = *(bh8*)&Bs_hi[r * 40 + quad * 8];
            bl[q] = *(bh8*)&Bs_lo[r * 40 + quad * 8];
        }
        #pragma unroll
        for (int p = 0; p < 4; p++)
            #pragma unroll
            for (int q = 0; q < 2; q++) {
                acc[p][q] = __builtin_amdgcn_mfma_f32_16x16x32_bf16(ah[p], bh[q], acc[p][q], 0, 0, 0);
                acc[p][q] = __builtin_amdgcn_mfma_f32_16x16x32_bf16(ah[p], bl[q], acc[p][q], 0, 0, 0);
                acc[p][q] = __builtin_amdgcn_mfma_f32_16x16x32_bf16(al[p], bh[q], acc[p][q], 0, 0, 0);
            }
        __syncthreads();
    }

    #pragma unroll
    for (int p = 0; p < 4; p++)
        #pragma unroll
        for (int q = 0; q < 2; q++) {
            int gcol = col0 + wc * 32 + q * 16 + m;
            #pragma unroll
            for (int r = 0; r < 4; r++) {
                int grow = row0 + wr * 64 + p * 16 + quad * 4 + r;
                C[(size_t)grow * ldc + gcol] = acc[p][q][r];
            }
        }
}

// ---------------------------------------------------------------------------
// scanA2: conv+silu + x_proj GEMM (3xbf16 MFMA, split-K over 8 waves) + dt +
// chunk-local scan, all in one block per (gb, chunk). Replaces gemm_xproj +
// old scanA. Writes XCb (for scanB), DBLc (for scanB), Aprod/Hend (combine).
// ---------------------------------------------------------------------------
__global__ __launch_bounds__(512) void scanA2(
    const float* __restrict__ XZ, const float* __restrict__ cw,
    const float* __restrict__ cb,
    const short* __restrict__ Wxh, const short* __restrict__ Wxl,
    const float* __restrict__ A_log, const float* __restrict__ Wdt,
    const float* __restrict__ bdt,
    float* __restrict__ XCb, float* __restrict__ DBLc,
    float* __restrict__ Aprod, float* __restrict__ Hend, int step)
{
    __shared__ short xcH[CL * XSTR];
    __shared__ short xcL[CL * XSTR];
    __shared__ float part[8][CL][48];
    __shared__ float dbl[CL][48];

    const int blk = blockIdx.x;
    const int c  = blk & (CH - 1);
    const int gb = blk >> 6;
    const int g  = gb >> 1;
    const int lay = g * 2 + step;
    const int d  = threadIdx.x;          // channel 0..511
    const int r0 = gb * L + c * CL;

    // ---- depthwise conv + silu for channel d, rows r0..r0+CL-1 ----
    float4 w4 = *(const float4*)&cw[((size_t)lay * DI + d) * 4];
    float cbv = cb[(size_t)lay * DI + d];
    float xz[CL + 3];
    #pragma unroll
    for (int j = 0; j < CL + 3; j++) {
        int lr = c * CL + j - 3;                  // local row in sequence
        xz[j] = (lr < 0) ? 0.f : XZ[(size_t)(gb * L + lr) * 1024 + d];
    }
    float xc[CL];
    #pragma unroll
    for (int tt = 0; tt < CL; tt++) {
        float v = cbv + w4.x * xz[tt] + w4.y * xz[tt + 1]
                      + w4.z * xz[tt + 2] + w4.w * xz[tt + 3];
        v = silu_f(v);
        xc[tt] = v;
        XCb[(size_t)(r0 + tt) * DI + d] = v;      // side product for scanB
        unsigned short hs = f2bf(v);
        xcH[tt * XSTR + d] = (short)hs;
        xcL[tt * XSTR + d] = (short)f2bf(v - bf2f(hs));
    }
    __syncthreads();

    // ---- dbl[16][48] = xc[16][512] @ Wx^T : 3xbf16 MFMA, split-K=64/wave ----
    {
        const int lane = d & 63, wv = d >> 6;
        const int m = lane & 15, quad = lane >> 4;
        const int ks = wv * 64;
        const size_t wb = (size_t)lay * 48 * DI;
        f4x acc[3] = {};
        #pragma unroll
        for (int kt = 0; kt < 2; kt++) {
            const int kb = ks + kt * 32 + quad * 8;
            bh8 ah = *(bh8*)&xcH[m * XSTR + kb];
            bh8 al = *(bh8*)&xcL[m * XSTR + kb];
            #pragma unroll
            for (int f = 0; f < 3; f++) {
                bh8 bh = *(const bh8*)&Wxh[wb + (size_t)(f * 16 + m) * DI + kb];
                bh8 bl = *(const bh8*)&Wxl[wb + (size_t)(f * 16 + m) * DI + kb];
                acc[f] = __builtin_amdgcn_mfma_f32_16x16x32_bf16(ah, bh, acc[f], 0, 0, 0);
                acc[f] = __builtin_amdgcn_mfma_f32_16x16x32_bf16(ah, bl, acc[f], 0, 0, 0);
                acc[f] = __builtin_amdgcn_mfma_f32_16x16x32_bf16(al, bh, acc[f], 0, 0, 0);
            }
        }
        #pragma unroll
        for (int f = 0; f < 3; f++)
            #pragma unroll
            for (int r = 0; r < 4; r++)
                part[wv][quad * 4 + r][f * 16 + m] = acc[f][r];
    }
    __syncthreads();

    for (int o = d; o < CL * 48; o += 512) {
        int tt = o / 48, cc = o - tt * 48;
        float v = 0.f;
        #pragma unroll
        for (int w = 0; w < 8; w++) v += part[w][tt][cc];
        dbl[tt][cc] = v;
        DBLc[(size_t)(r0 + tt) * 48 + cc] = v;    // compact side-write for scanB
    }

    // ---- dt + chunk-local scan ----
    float wdt[16];
    const float* wrow = Wdt + ((size_t)lay * DI + d) * DR;
    #pragma unroll
    for (int k = 0; k < 16; k += 4) {
        float4 v = *(const float4*)&wrow[k];
        wdt[k] = v.x; wdt[k + 1] = v.y; wdt[k + 2] = v.z; wdt[k + 3] = v.w;
    }
    float bias = bdt[(size_t)lay * DI + d];

    float a[DS], h[DS], ap[DS];
    const float* al = A_log + ((size_t)lay * DI + d) * DS;
    #pragma unroll
    for (int s = 0; s < DS; s++) { a[s] = -__expf(al[s]); h[s] = 0.f; ap[s] = 1.f; }
    __syncthreads();

    for (int tt = 0; tt < CL; tt++) {
        float dtr = bias;
        #pragma unroll
        for (int k = 0; k < 16; k++) dtr += dbl[tt][k] * wdt[k];
        float dt = softplus_f(dtr);
        float dx = dt * xc[tt];
        #pragma unroll
        for (int s = 0; s < DS; s++) {
            float da = __expf(dt * a[s]);
            h[s] = da * h[s] + dx * dbl[tt][16 + s];
            ap[s] *= da;
        }
    }
    size_t base = ((size_t)(gb * DI + d) * CH + c) * DS;
    #pragma unroll
    for (int q = 0; q < 4; q++) {
        *(float4*)&Aprod[base + q * 4] = make_float4(ap[q*4], ap[q*4+1], ap[q*4+2], ap[q*4+3]);
        *(float4*)&Hend [base + q * 4] = make_float4(h[q*4],  h[q*4+1],  h[q*4+2],  h[q*4+3]);
    }
}

// ---------------------------------------------------------------------------
// Combine: serial exclusive scan over CH chunks per (gb,d,s) lane. (baseline)
// ---------------------------------------------------------------------------
__global__ __launch_bounds__(256) void scanCombine(
    const float* __restrict__ Aprod, const float* __restrict__ Hend,
    float* __restrict__ Hinit)
{
    int idx = blockIdx.x * 256 + threadIdx.x;  // (gb*DI+d)*DS + s
    int s  = idx & 15;
    int gd = idx >> 4;
    size_t base = (size_t)gd * CH * DS + s;
    float h = 0.f;
    for (int c0 = 0; c0 < CH; c0 += 8) {
        float ap[8], e[8];
        #pragma unroll
        for (int j = 0; j < 8; j++) {
            size_t o = base + (size_t)(c0 + j) * DS;
            ap[j] = Aprod[o]; e[j] = Hend[o];
        }
        #pragma unroll
        for (int j = 0; j < 8; j++) {
            Hinit[base + (size_t)(c0 + j) * DS] = h;
            h = ap[j] * h + e[j];
        }
    }
}

// ---------------------------------------------------------------------------
// Scan phase B + FUSED out_proj (baseline, unchanged): dbl from compact DBLc;
// replay with h_init, y -> LDS (bf16 hi/lo), per-wave 3xbf16 MFMA epilogue.
// OUTMODE 0: write Pout as bf16 hi/lo pairs. OUTMODE 1: scatter fp32 to d_out.
// ---------------------------------------------------------------------------
template<int OUTMODE>
__global__ __launch_bounds__(512) void scanB_fused(
    const float* __restrict__ XCb, const float* __restrict__ DBLc,
    const float* __restrict__ XZ, const float* __restrict__ A_log,
    const float* __restrict__ Wdt, const float* __restrict__ bdt,
    const float* __restrict__ Dp, const float* __restrict__ Hinit,
    const short* __restrict__ Woh, const short* __restrict__ Wol,
    float* __restrict__ Cout, short* __restrict__ Ph, short* __restrict__ Pl,
    int step)
{
    __shared__ float dbl[CL][48];
    __shared__ short Ys_hi[CL * YSTR];
    __shared__ short Ys_lo[CL * YSTR];
    int blk = blockIdx.x;
    int c  = blk & (CH - 1);
    int gb = blk >> 6;
    int g  = gb >> 1;
    int lay = g * 2 + step;
    int d = threadIdx.x;
    int r0 = gb * L + c * CL;

    for (int id = threadIdx.x; id < CL * 48; id += 512) {
        int rr = id / 48, cc = id - rr * 48;
        dbl[rr][cc] = DBLc[(size_t)(r0 + rr) * 48 + cc];
    }

    float xc[CL], zz[CL];
    #pragma unroll
    for (int tt = 0; tt < CL; tt++) xc[tt] = XCb[(size_t)(r0 + tt) * DI + d];
    #pragma unroll
    for (int tt = 0; tt < CL; tt++) zz[tt] = XZ[(size_t)(r0 + tt) * 1024 + 512 + d];

    float wdt[16];
    const float* wrow = Wdt + ((size_t)lay * DI + d) * DR;
    #pragma unroll
    for (int k = 0; k < 16; k += 4) {
        float4 v = *(const float4*)&wrow[k];
        wdt[k] = v.x; wdt[k + 1] = v.y; wdt[k + 2] = v.z; wdt[k + 3] = v.w;
    }
    float bias = bdt[(size_t)lay * DI + d];

    float a[DS], h[DS];
    const float* al = A_log + ((size_t)lay * DI + d) * DS;
    size_t base = ((size_t)(gb * DI + d) * CH + c) * DS;
    #pragma unroll
    for (int q = 0; q < 4; q++) {
        float4 hv = *(const float4*)&Hinit[base + q * 4];
        h[q*4] = hv.x; h[q*4+1] = hv.y; h[q*4+2] = hv.z; h[q*4+3] = hv.w;
    }
    #pragma unroll
    for (int s = 0; s < DS; s++) a[s] = -__expf(al[s]);
    float Dv = Dp[(size_t)lay * DI + d];
    __syncthreads();

    #pragma unroll
    for (int tt = 0; tt < CL; tt++) {
        float dtr = bias;
        #pragma unroll
        for (int k = 0; k < 16; k++) dtr += dbl[tt][k] * wdt[k];
        float dt = softplus_f(dtr);
        float dx = dt * xc[tt];
        float y = 0.f;
        #pragma unroll
        for (int s = 0; s < DS; s++) {
            float da = __expf(dt * a[s]);
            h[s] = da * h[s] + dx * dbl[tt][16 + s];
            y += h[s] * dbl[tt][32 + s];
        }
        y += xc[tt] * Dv;
        y *= silu_f(zz[tt]);
        unsigned short hs = f2bf(y);
        Ys_hi[tt * YSTR + d] = (short)hs;
        Ys_lo[tt * YSTR + d] = (short)f2bf(y - bf2f(hs));
    }
    __syncthreads();

    // ---- fused out_proj epilogue: 16 rows x 256 cols, K=512 ----
    const int lane = threadIdx.x & 63, wv = threadIdx.x >> 6;
    const int m = lane & 15, quad = lane >> 4;
    const size_t wbase = (size_t)lay * DM * DI;

    #pragma unroll
    for (int q = 0; q < 2; q++) {
        const int coln = wv * 32 + q * 16 + m;
        const size_t wrow2 = wbase + (size_t)coln * DI;
        bh8 wh[16], wl[16];
        #pragma unroll
        for (int i = 0; i < 16; i++) {
            const int kk = i * 32 + quad * 8;
            wh[i] = *(const bh8*)&Woh[wrow2 + kk];
            wl[i] = *(const bh8*)&Wol[wrow2 + kk];
        }
        f4x acc = {};
        #pragma unroll
        for (int i = 0; i < 16; i++) {
            const int kk = i * 32 + quad * 8;
            bh8 ahv = *(bh8*)&Ys_hi[m * YSTR + kk];
            bh8 alv = *(bh8*)&Ys_lo[m * YSTR + kk];
            acc = __builtin_amdgcn_mfma_f32_16x16x32_bf16(ahv, wh[i], acc, 0, 0, 0);
            acc = __builtin_amdgcn_mfma_f32_16x16x32_bf16(ahv, wl[i], acc, 0, 0, 0);
            acc = __builtin_amdgcn_mfma_f32_16x16x32_bf16(alv, wh[i], acc, 0, 0, 0);
        }
        #pragma unroll
        for (int r = 0; r < 4; r++) {
            int tt = quad * 4 + r;
            int grow = r0 + tt;
            if (OUTMODE == 0) {
                size_t o = (size_t)grow * DM + coln;
                unsigned short hs = f2bf(acc[r]);
                Ph[o] = (short)hs;
                Pl[o] = (short)f2bf(acc[r] - bf2f(hs));
            } else {
                int b = (grow >> 10) & 1, l = grow & 1023;
                size_t dst = (g == 0)
                    ? ((size_t)(b * 1024 + l) * 512 + coln)
                    : ((size_t)(b * 1024 + (1023 - l)) * 512 + 256 + coln);
                Cout[dst] = acc[r];
            }
        }
    }
}

extern "C" void kernel_launch(void* const* d_in, const int* in_sizes, int n_in,
                              void* d_out, int out_size, void* d_ws, size_t ws_size,
                              hipStream_t stream)
{
    const float* x        = (const float*)d_in[0];
    const float* in_proj  = (const float*)d_in[1];
    const float* conv_w   = (const float*)d_in[2];
    const float* conv_b   = (const float*)d_in[3];
    const float* x_proj   = (const float*)d_in[4];
    const float* dt_proj  = (const float*)d_in[5];
    const float* dt_bias  = (const float*)d_in[6];
    const float* A_log    = (const float*)d_in[7];
    const float* Dp       = (const float*)d_in[8];
    const float* out_proj = (const float*)d_in[9];
    float* out = (float*)d_out;

    float* w = (float*)d_ws;
    size_t o = 0;
    float* XZ    = w + o; o += (size_t)RTOT * 1024;
    float* XCb   = w + o; o += (size_t)RTOT * DI;
    float* Pdbl  = w + o; o += (size_t)8 * RTOT * 48;      // reused: Wxh/Wxl live here
    float* DBLc  = w + o; o += (size_t)RTOT * 48;
    float* Aprod = w + o; o += (size_t)G * BB * DI * CH * DS;
    float* Hend  = w + o; o += (size_t)G * BB * DI * CH * DS;
    float* Hinit = w + o; o += (size_t)G * BB * DI * CH * DS;
    short* Wih   = (short*)(w + o); o += NWIN / 2;
    short* Wil   = (short*)(w + o); o += NWIN / 2;
    short* Woh   = (short*)(w + o); o += NWOUT / 2;
    short* Wol   = (short*)(w + o); o += NWOUT / 2;
    short* Ph    = (short*)(w + o); o += (size_t)RTOT * DM / 2;
    short* Pl    = (short*)(w + o); o += (size_t)RTOT * DM / 2;
    // x_proj bf16 hi/lo carved out of the now-unused Pdbl slab (6.3 MB >> 0.4 MB)
    short* Wxh   = (short*)Pdbl;
    short* Wxl   = Wxh + NWX;
    (void)ws_size; (void)in_sizes; (void)n_in; (void)out_size;

    // one-time weight pre-conversion (fp32 -> bf16 hi/lo), single dispatch
    {
        int n4a = NWIN / 4, n4b = NWOUT / 4, n4c = NWX / 4;
        cvtW3<<<(n4a + n4b + n4c + 255) / 256, 256, 0, stream>>>(
            in_proj, Wih, Wil, n4a, out_proj, Woh, Wol, n4b,
            x_proj, Wxh, Wxl, n4c);
    }

    for (int step = 0; step < 2; step++) {
        // in_proj: 4096x1024, K=256, MFMA 3xbf16. 128x64 tiles -> 512 blocks.
        if (step == 0)
            mfma_inproj<1><<<dim3(16, 32), 256, 0, stream>>>(
                x, nullptr, nullptr, Wih, Wil, 0, XZ);
        else
            mfma_inproj<0><<<dim3(16, 32), 256, 0, stream>>>(
                nullptr, Ph, Pl, Wih, Wil, 1, XZ);

        // fused conv+silu + x_proj MFMA + dt + chunk scan: 256 blocks.
        scanA2<<<G * BB * CH, 512, 0, stream>>>(
            XZ, conv_w, conv_b, Wxh, Wxl, A_log, dt_proj, dt_bias,
            XCb, DBLc, Aprod, Hend, step);

        scanCombine<<<(G * BB * DI * DS) / 256, 256, 0, stream>>>(Aprod, Hend, Hinit);

        if (step == 0)
            scanB_fused<0><<<G * BB * CH, 512, 0, stream>>>(
                XCb, DBLc, XZ, A_log, dt_proj, dt_bias, Dp, Hinit,
                Woh, Wol, nullptr, Ph, Pl, 0);
        else
            scanB_fused<1><<<G * BB * CH, 512, 0, stream>>>(
                XCb, DBLc, XZ, A_log, dt_proj, dt_bias, Dp, Hinit,
                Woh, Wol, out, nullptr, nullptr, 1);
    }
}